// Round 8
// baseline (13568.752 us; speedup 1.0000x reference)
//
#include <hip/hip_runtime.h>

typedef float f32x4  __attribute__((ext_vector_type(4)));
typedef float f32x16 __attribute__((ext_vector_type(16)));
typedef short short8 __attribute__((ext_vector_type(8)));
typedef int   intx4  __attribute__((ext_vector_type(4)));

#define TT 1024
#define DD 512
#define BTD (32u*1024u*512u)
#define SLOT_SH 16384      // shorts per slot (32KB); 1024 slots, written once each
#define SENTD  0xFF80FF80u

__device__ __forceinline__ unsigned short f2bf(float f){
  unsigned int u = __float_as_uint(f);
  u += 0x7FFFu + ((u >> 16) & 1u);          // round-to-nearest-even
  return (unsigned short)(u >> 16);
}
__device__ __forceinline__ float bf2f(unsigned short s){
  return __uint_as_float(((unsigned)s) << 16);
}
__device__ __forceinline__ float fast_tanh(float x){
  float ax = fabsf(x);
  float e  = __expf(2.0f*ax);
  float r  = 1.0f - 2.0f/(e + 1.0f);
  return x < 0.f ? -r : r;
}
__device__ __forceinline__ unsigned umaxu(unsigned a, unsigned b){ return a > b ? a : b; }

// ---------------- prep: sentinel-fill the 32MB ring ----------------
__global__ void prep_ring_k(uint4* __restrict__ p){
  const size_t n = (size_t)TT * SLOT_SH / 8;
  uint4 s = make_uint4(SENTD, SENTD, SENTD, SENTD);
  for (size_t i = blockIdx.x*(size_t)blockDim.x + threadIdx.x; i < n;
       i += (size_t)gridDim.x*blockDim.x)
    p[i] = s;
}

// ---------------- prep: z, packed weights, d_init (fragment layout) ----------------
__global__ void prep_misc_k(const float* __restrict__ A, const float* __restrict__ noise,
                            const float* __restrict__ Wd, const float* __restrict__ Wz,
                            const float* __restrict__ Wdz, const float* __restrict__ Whd,
                            const float* __restrict__ init_h,
                            unsigned short* __restrict__ zbf, unsigned short* __restrict__ Wu,
                            unsigned short* __restrict__ Wp, unsigned short* __restrict__ Wdzp,
                            unsigned short* __restrict__ dinit){
  const unsigned NZ = 2097152u, NWU = 294912u, NWP = 262144u, NWZ = 65536u, ND = 16384u;
  const unsigned NT = NZ + NWU + NWP + NWZ + ND;
  for (unsigned i = blockIdx.x*blockDim.x + threadIdx.x; i < NT; i += gridDim.x*blockDim.x){
    if (i < NZ){                                   // z = tanh(mu_in_q) + noise*exp(ln_q)
      unsigned m = i >> 6, zi = i & 63u;
      float muin = A[(size_t)m*128u + zi];
      float ln   = A[(size_t)m*128u + 64u + zi];
      zbf[i] = f2bf(fast_tanh(muin) + noise[i]*__expf(ln));
    } else if (i < NZ+NWU){                        // Wu[c][kk]: [Whd | Wz], [512][576]
      unsigned j = i - NZ;
      unsigned c = j / 576u, kk = j - c*576u;
      float v = (kk < 512u) ? Whd[(size_t)c*512u + kk] : Wz[(size_t)c*64u + (kk-512u)];
      Wu[j] = f2bf(v);
    } else if (i < NZ+NWU+NWP){                    // Wp[c][k] = Wd, [512][512]
      unsigned j = i - (NZ+NWU);
      Wp[j] = f2bf(Wd[j]);
    } else if (i < NZ+NWU+NWP+NWZ){                // Wdzp = bf16(Wdz), [128][512]
      unsigned j = i - (NZ+NWU+NWP);
      Wdzp[j] = f2bf(Wdz[j]);
    } else {                                       // d_{-1} = tanh(init_h), fragment layout
      unsigned j = i - (NZ+NWU+NWP+NWZ);
      unsigned b = j >> 9, c = j & 511u;
      unsigned idx = ((c>>4)<<9) + (((c>>3)&1u)<<8) + (b<<3) + (c&7u);
      dinit[idx] = f2bf(fast_tanh(init_h[j]));
    }
  }
}

// ---------------- wnll_init_h -> d_out[BTD] ----------------
__global__ void wnll_k(const float* __restrict__ init_h, const float* __restrict__ mu,
                       float* __restrict__ dout){
  __shared__ float red[256];
  float s = 0.f;
  for (unsigned i = threadIdx.x; i < 16384u; i += 256u){
    float x = init_h[i] - mu[i & 511u];
    s += 0.5f*x*x;
  }
  red[threadIdx.x] = s; __syncthreads();
  for (int st = 128; st > 0; st >>= 1){
    if ((int)threadIdx.x < st) red[threadIdx.x] += red[threadIdx.x + st];
    __syncthreads();
  }
  if (threadIdx.x == 0){
    float nll = (red[0] + 16384.0f*0.91893853320467274f) / 512.0f;
    dout[(size_t)BTD] = 1e-3f * nll;
  }
}

// ---------------- U = (X @ Wu^T + bias)/tau  into d_out (f32) ----------------
__global__ __launch_bounds__(256) void gemm_u_k(
    const float* __restrict__ hd,             // [32768][512] f32
    const unsigned short* __restrict__ Xz,    // [32768][64]  bf16
    const unsigned short* __restrict__ Wu,    // [512][576]   bf16
    const float* __restrict__ bias,
    float* __restrict__ dout)
{
  __shared__ __align__(16) unsigned short Xs[128][40];
  __shared__ __align__(16) unsigned short Ws[128][40];
  const int bm = blockIdx.x >> 2;
  const int bn = blockIdx.x & 3;
  const int tid = threadIdx.x;
  const int lane = tid & 63;
  const int wv = tid >> 6;
  const int m0 = (wv >> 1) * 64, c0 = (wv & 1) * 64;
  f32x4 acc[4][4];
  #pragma unroll
  for (int i=0;i<4;++i)
    #pragma unroll
    for (int j=0;j<4;++j)
      #pragma unroll
      for (int r=0;r<4;++r) acc[i][j][r] = 0.f;

  const int sm = tid >> 1;
  const int sk = (tid & 1) * 16;
  for (int kt = 0; kt < 18; ++kt){
    __syncthreads();
    {
      int mg = bm*128 + sm;
      if (kt < 16){
        const float* src = hd + (size_t)mg*512u + (unsigned)(kt*32 + sk);
        uint2 o[4];
        #pragma unroll
        for (int q=0;q<4;++q){
          f32x4 v = *reinterpret_cast<const f32x4*>(src + 4*q);
          o[q].x = (unsigned)f2bf(v[0]) | ((unsigned)f2bf(v[1])<<16);
          o[q].y = (unsigned)f2bf(v[2]) | ((unsigned)f2bf(v[3])<<16);
        }
        *reinterpret_cast<uint4*>(&Xs[sm][sk])   = make_uint4(o[0].x,o[0].y,o[1].x,o[1].y);
        *reinterpret_cast<uint4*>(&Xs[sm][sk+8]) = make_uint4(o[2].x,o[2].y,o[3].x,o[3].y);
      } else {
        const unsigned short* src = Xz + (size_t)mg*64u + (unsigned)((kt-16)*32 + sk);
        uint4 v0 = *reinterpret_cast<const uint4*>(src);
        uint4 v1 = *reinterpret_cast<const uint4*>(src + 8);
        *reinterpret_cast<uint4*>(&Xs[sm][sk])   = v0;
        *reinterpret_cast<uint4*>(&Xs[sm][sk+8]) = v1;
      }
      int cg = bn*128 + sm;
      const unsigned short* wsrc = Wu + (size_t)cg*576u + (unsigned)(kt*32 + sk);
      uint4 w0 = *reinterpret_cast<const uint4*>(wsrc);
      uint4 w1 = *reinterpret_cast<const uint4*>(wsrc + 8);
      *reinterpret_cast<uint4*>(&Ws[sm][sk])   = w0;
      *reinterpret_cast<uint4*>(&Ws[sm][sk+8]) = w1;
    }
    __syncthreads();
    short8 af[4], bf[4];
    #pragma unroll
    for (int i=0;i<4;++i)
      af[i] = *reinterpret_cast<const short8*>(&Xs[m0 + i*16 + (lane&15)][(lane>>4)*8]);
    #pragma unroll
    for (int j=0;j<4;++j)
      bf[j] = *reinterpret_cast<const short8*>(&Ws[c0 + j*16 + (lane&15)][(lane>>4)*8]);
    #pragma unroll
    for (int i=0;i<4;++i)
      #pragma unroll
      for (int j=0;j<4;++j)
        acc[i][j] = __builtin_amdgcn_mfma_f32_16x16x32_bf16(af[i], bf[j], acc[i][j], 0, 0, 0);
  }
  #pragma unroll
  for (int j=0;j<4;++j){
    int cg = bn*128 + c0 + j*16 + (lane&15);
    float bia  = bias[cg];
    float itau = (cg < 256) ? 0.25f : 0.5f;
    #pragma unroll
    for (int i=0;i<4;++i){
      int mbase = bm*128 + m0 + i*16 + (lane>>4)*4;
      #pragma unroll
      for (int r=0;r<4;++r)
        dout[(size_t)(mbase + r)*512u + cg] = (acc[i][j][r] + bia) * itau;
    }
  }
}

// ---------------- persistent serial recurrence: 2 compute WGs + LDS local half ----------------
// grid = 4 WGs x 512.  WG 0,1: compute (8 waves x 32 cols = 256 cols each).
// Local half of d exchanged via LDS frag-layout double buffer + __syncthreads.
// Remote half (16KB) via write-once sentinel ring (round-7 fabric, sc0 sc1).
// WG 2,3: d_seq writers (16 wave-portions of 2KB/slot), sentinel-validated.
__global__ __launch_bounds__(512,1) void recur_k(
    float* __restrict__ dout, const float* __restrict__ init_h,
    const unsigned short* __restrict__ Wp, const unsigned short* __restrict__ dinit,
    unsigned short* __restrict__ dcomm)
{
  __shared__ __align__(16) unsigned short lbuf[2][8192];   // 2 x 16KB local-half frags
  const int wg   = blockIdx.x;
  const int tid  = threadIdx.x;
  const int lane = tid & 63;
  const int w    = tid >> 6;

  // ================= writer WGs =================
  if (wg >= 2){
    const int wid = (wg - 2)*8 + w;               // 0..15, owns 2KB of each slot
    const int b   = lane & 31;
    const int cb0 = wid*32 + (lane>>5)*8;
    for (int t = 0; t < TT; ++t){
      const char* base = (const char*)dcomm + (size_t)t*32768 + wid*2048 + lane*16;
      intx4 q0, q1;
      for (;;){
        asm volatile(
          "global_load_dwordx4 %0, %2, off sc0 sc1\n\t"
          "global_load_dwordx4 %1, %2, off offset:1024 sc0 sc1\n\t"
          "s_waitcnt vmcnt(0)"
          : "=&v"(q0), "=&v"(q1) : "v"(base) : "memory");
        unsigned mx = umaxu(umaxu(umaxu((unsigned)q0[0],(unsigned)q0[1]),
                                  umaxu((unsigned)q0[2],(unsigned)q0[3])),
                            umaxu(umaxu((unsigned)q1[0],(unsigned)q1[1]),
                                  umaxu((unsigned)q1[2],(unsigned)q1[3])));
        if (__all(mx < 0xC0000000u)) break;
      }
      __builtin_amdgcn_sched_barrier(0);
      float* drow = dout + ((size_t)b*TT + t)*DD;
      union { intx4 i; short8 s; } c0, c1; c0.i = q0; c1.i = q1;
      f32x4 o0, o1, o2, o3;
      #pragma unroll
      for (int e=0;e<4;++e){
        o0[e] = bf2f((unsigned short)c0.s[e]);
        o1[e] = bf2f((unsigned short)c0.s[4+e]);
        o2[e] = bf2f((unsigned short)c1.s[e]);
        o3[e] = bf2f((unsigned short)c1.s[4+e]);
      }
      *reinterpret_cast<f32x4*>(drow + cb0)          = o0;
      *reinterpret_cast<f32x4*>(drow + cb0 + 4)      = o1;
      *reinterpret_cast<f32x4*>(drow + cb0 + 16)     = o2;
      *reinterpret_cast<f32x4*>(drow + cb0 + 16 + 4) = o3;
    }
    return;
  }

  // ================= compute WGs =================
  const int g     = wg;                           // 0 or 1: col half
  const int pc    = g*256 + w*32 + (lane & 31);   // global column
  const int khalf = (lane >> 5) * 8;
  const int bof   = (lane >> 5) * 4;

  // B-fragments: local k-half and remote k-half
  short8 wfL[16], wfR[16];
  #pragma unroll
  for (int j = 0; j < 16; ++j){
    wfL[j] = *reinterpret_cast<const short8*>(Wp + (size_t)pc*512u + (unsigned)((16*g    +j)*16 + khalf));
    wfR[j] = *reinterpret_cast<const short8*>(Wp + (size_t)pc*512u + (unsigned)((16*(1-g)+j)*16 + khalf));
  }

  const float dec  = (pc < 256) ? 0.75f : 0.5f;
  const float itau = (pc < 256) ? 0.25f : 0.5f;

  float h[16];
  #pragma unroll
  for (int r=0;r<16;++r){
    int b = (r&3) + 8*(r>>2) + bof;
    h[r] = init_h[b*512 + pc];
  }
  float u[16];
  #pragma unroll
  for (int r=0;r<16;++r){
    int b = (r&3) + 8*(r>>2) + bof;
    u[r] = dout[((size_t)b*TT + 0)*DD + pc];
  }

  // preload LDS buf[1] with the local half of dinit (wave w owns chunks 2w, 2w+1)
  {
    const unsigned short* src = dinit + (size_t)(16*g + 2*w)*512u + lane*8;
    short8 a0 = *reinterpret_cast<const short8*>(src);
    short8 a1 = *reinterpret_cast<const short8*>(src + 512);
    *reinterpret_cast<short8*>(&lbuf[1][(2*w)*512 + lane*8])   = a0;
    *reinterpret_cast<short8*>(&lbuf[1][(2*w+1)*512 + lane*8]) = a1;
  }
  __syncthreads();

  const int jlw = 2*w + ((lane & 31) >> 4);   // local chunk this lane's column is in
  const int khw = ((lane & 31) >> 3) & 1;     // k-half within chunk
  const int c7  = lane & 7;

  union CV { intx4 i; short8 s; };

  for (int t = 0; t < TT; ++t){
    // issue remote-half gather early (hides under local MFMA)
    const char* rbase = (t == 0)
        ? (const char*)dinit + (1-g)*16384
        : (const char*)dcomm + (size_t)(t-1)*32768 + (1-g)*16384;
    const char* bp0 = rbase + lane*16;
    intx4 fi[16];
    #pragma unroll
    for (int g2 = 0; g2 < 4; ++g2){
      const char* bp = bp0 + g2*4096;
      asm volatile(
        "global_load_dwordx4 %0, %4, off sc0 sc1\n\t"
        "global_load_dwordx4 %1, %4, off offset:1024 sc0 sc1\n\t"
        "global_load_dwordx4 %2, %4, off offset:2048 sc0 sc1\n\t"
        "global_load_dwordx4 %3, %4, off offset:3072 sc0 sc1"
        : "=&v"(fi[4*g2]), "=&v"(fi[4*g2+1]), "=&v"(fi[4*g2+2]), "=&v"(fi[4*g2+3])
        : "v"(bp) : "memory");
    }

    // local-half MFMA from LDS (buf written at end of step t-1)
    f32x16 acc0, acc1;
    #pragma unroll
    for (int q=0;q<16;++q){ acc0[q]=0.f; acc1[q]=0.f; }
    const unsigned short* rb = lbuf[(t & 1) ^ 1];
    #pragma unroll
    for (int j = 0; j < 8; ++j){
      short8 a0 = *reinterpret_cast<const short8*>(&rb[(2*j)*512   + lane*8]);
      short8 a1 = *reinterpret_cast<const short8*>(&rb[(2*j+1)*512 + lane*8]);
      acc0 = __builtin_amdgcn_mfma_f32_32x32x16_bf16(a0, wfL[2*j  ], acc0, 0, 0, 0);
      acc1 = __builtin_amdgcn_mfma_f32_32x32x16_bf16(a1, wfL[2*j+1], acc1, 0, 0, 0);
    }

    // drain + validate remote half; retry with full re-issue if sentinel
    for (;;){
      asm volatile("s_waitcnt vmcnt(0)" ::: "memory");
      __builtin_amdgcn_sched_barrier(0);
      unsigned mx = 0u;
      #pragma unroll
      for (int j=0;j<16;++j){
        mx = umaxu(mx, umaxu(umaxu((unsigned)fi[j][0],(unsigned)fi[j][1]),
                             umaxu((unsigned)fi[j][2],(unsigned)fi[j][3])));
      }
      if (__all(mx < 0xC0000000u)) break;
      #pragma unroll
      for (int g2 = 0; g2 < 4; ++g2){
        const char* bp = bp0 + g2*4096;
        asm volatile(
          "global_load_dwordx4 %0, %4, off sc0 sc1\n\t"
          "global_load_dwordx4 %1, %4, off offset:1024 sc0 sc1\n\t"
          "global_load_dwordx4 %2, %4, off offset:2048 sc0 sc1\n\t"
          "global_load_dwordx4 %3, %4, off offset:3072 sc0 sc1"
          : "=&v"(fi[4*g2]), "=&v"(fi[4*g2+1]), "=&v"(fi[4*g2+2]), "=&v"(fi[4*g2+3])
          : "v"(bp) : "memory");
      }
    }

    // prefetch next-step U (cached; completes long before next drain)
    float un[16];
    if (t+1 < TT){
      #pragma unroll
      for (int r=0;r<16;++r){
        int b = (r&3) + 8*(r>>2) + bof;
        un[r] = dout[((size_t)b*TT + (t+1))*DD + pc];
      }
    }

    // remote-half MFMA
    #pragma unroll
    for (int j = 0; j < 8; ++j){
      CV c0, c1; c0.i = fi[2*j]; c1.i = fi[2*j+1];
      acc0 = __builtin_amdgcn_mfma_f32_32x32x16_bf16(c0.s, wfR[2*j  ], acc0, 0, 0, 0);
      acc1 = __builtin_amdgcn_mfma_f32_32x32x16_bf16(c1.s, wfR[2*j+1], acc1, 0, 0, 0);
    }

    // h update + tanh
    float dv[16];
    #pragma unroll
    for (int r=0;r<16;++r){
      float P = acc0[r] + acc1[r];
      h[r]  = dec*h[r] + P*itau + u[r];
      dv[r] = fast_tanh(h[r]);
    }

    // write local frag-layout LDS (buf[t&1]) for next step's local MFMA
    unsigned short* wb = lbuf[t & 1];
    #pragma unroll
    for (int r=0;r<16;++r){
      int b = (r&3) + 8*(r>>2) + bof;
      wb[jlw*512 + b*8 + khw*256 + c7] = f2bf(dv[r]);
    }
    // read back own 2 chunks (same-wave LDS dependency) and publish to ring
    {
      short8 v0 = *reinterpret_cast<const short8*>(&wb[(2*w)*512   + lane*8]);
      short8 v1 = *reinterpret_cast<const short8*>(&wb[(2*w+1)*512 + lane*8]);
      unsigned short* ds = dcomm + (size_t)t*SLOT_SH + (16*g + 2*w)*512 + lane*8;
      asm volatile("global_store_dwordx4 %0, %2, off sc0 sc1\n\t"
                   "global_store_dwordx4 %1, %3, off sc0 sc1"
                   :: "v"(ds), "v"(ds + 512), "v"(v0), "v"(v1) : "memory");
    }
    __syncthreads();   // buf[t&1] complete for all waves
    if (t+1 < TT){
      #pragma unroll
      for (int r=0;r<16;++r) u[r] = un[r];
    }
  }
}

// ---------------- epilogue: prior_in = d_shifted @ Wdz^T, fused KL -> atomicAdd ----------------
__global__ __launch_bounds__(256) void gemm_p_k(
    const float* __restrict__ dseq,           // dout: [32][1024][512] f32
    const unsigned short* __restrict__ Wdzp,  // [128][512] bf16
    const float* __restrict__ A,              // [32768][128] f32
    float* __restrict__ dout)
{
  __shared__ __align__(16) unsigned short Xs[128][40];
  __shared__ __align__(16) unsigned short Ws[128][40];
  __shared__ float Ls[128][128];
  __shared__ float red[256];
  const int bm = blockIdx.x;
  const int tid = threadIdx.x;
  const int lane = tid & 63;
  const int wv = tid >> 6;
  const int m0 = (wv >> 1) * 64, c0 = (wv & 1) * 64;
  f32x4 acc[4][4];
  #pragma unroll
  for (int i=0;i<4;++i)
    #pragma unroll
    for (int j=0;j<4;++j)
      #pragma unroll
      for (int r=0;r<4;++r) acc[i][j][r] = 0.f;

  const int sm = tid >> 1;
  const int sk = (tid & 1) * 16;
  for (int kt = 0; kt < 16; ++kt){
    __syncthreads();
    {
      int mg = bm*128 + sm;
      int ttm = mg & 1023;
      int srow = (ttm == 0) ? mg : (mg - 1);       // d[b][t-1]; t==0 rows overridden in KL
      const float* src = dseq + (size_t)srow*512u + (unsigned)(kt*32 + sk);
      uint2 o[4];
      #pragma unroll
      for (int q=0;q<4;++q){
        f32x4 v = *reinterpret_cast<const f32x4*>(src + 4*q);
        o[q].x = (unsigned)f2bf(v[0]) | ((unsigned)f2bf(v[1])<<16);
        o[q].y = (unsigned)f2bf(v[2]) | ((unsigned)f2bf(v[3])<<16);
      }
      *reinterpret_cast<uint4*>(&Xs[sm][sk])   = make_uint4(o[0].x,o[0].y,o[1].x,o[1].y);
      *reinterpret_cast<uint4*>(&Xs[sm][sk+8]) = make_uint4(o[2].x,o[2].y,o[3].x,o[3].y);
      const unsigned short* wsrc = Wdzp + (size_t)sm*512u + (unsigned)(kt*32 + sk);
      uint4 w0 = *reinterpret_cast<const uint4*>(wsrc);
      uint4 w1 = *reinterpret_cast<const uint4*>(wsrc + 8);
      *reinterpret_cast<uint4*>(&Ws[sm][sk])   = w0;
      *reinterpret_cast<uint4*>(&Ws[sm][sk+8]) = w1;
    }
    __syncthreads();
    short8 af[4], bf[4];
    #pragma unroll
    for (int i=0;i<4;++i)
      af[i] = *reinterpret_cast<const short8*>(&Xs[m0 + i*16 + (lane&15)][(lane>>4)*8]);
    #pragma unroll
    for (int j=0;j<4;++j)
      bf[j] = *reinterpret_cast<const short8*>(&Ws[c0 + j*16 + (lane&15)][(lane>>4)*8]);
    #pragma unroll
    for (int i=0;i<4;++i)
      #pragma unroll
      for (int j=0;j<4;++j)
        acc[i][j] = __builtin_amdgcn_mfma_f32_16x16x32_bf16(af[i], bf[j], acc[i][j], 0, 0, 0);
  }
  #pragma unroll
  for (int j=0;j<4;++j){
    int cc = c0 + j*16 + (lane&15);
    #pragma unroll
    for (int i=0;i<4;++i){
      int mm = m0 + i*16 + (lane>>4)*4;
      #pragma unroll
      for (int r=0;r<4;++r)
        Ls[mm + r][cc] = acc[i][j][r];
    }
  }
  __syncthreads();
  float ks = 0.f;
  const int z = tid & 63;
  for (int ml = (tid >> 6); ml < 128; ml += 4){
    int mg = bm*128 + ml;
    int ttm = mg & 1023;
    const float* ap = A + (size_t)mg*128u;
    float mq = fast_tanh(ap[z]);
    float sq = __expf(ap[64 + z]);
    float mp = (ttm == 0) ? 0.f : fast_tanh(Ls[ml][z]);
    float sp = (ttm == 0) ? 1.f : __expf(Ls[ml][64 + z]);
    float dm = mq - mp;
    ks += __logf(sp + 1e-6f) - __logf(sq + 1e-6f) - 0.5f
        + 0.5f*(dm*dm + sq*sq)/(sp*sp + 1e-6f);
  }
  red[tid] = ks; __syncthreads();
  for (int st = 128; st > 0; st >>= 1){
    if (tid < st) red[tid] += red[tid + st];
    __syncthreads();
  }
  if (tid == 0) atomicAdd(dout + (size_t)BTD, red[0] * (1e-3f/64.f));
}

extern "C" void kernel_launch(void* const* d_in, const int* in_sizes, int n_in,
                              void* d_out, int out_size, void* d_ws, size_t ws_size,
                              hipStream_t stream){
  const float* hd        = (const float*)d_in[0];
  const float* A         = (const float*)d_in[1];
  const float* noise     = (const float*)d_in[2];
  const float* Wd        = (const float*)d_in[3];
  const float* Wz        = (const float*)d_in[4];
  const float* Wdz       = (const float*)d_in[5];
  const float* Whd       = (const float*)d_in[6];
  const float* bias      = (const float*)d_in[7];
  const float* init_h    = (const float*)d_in[8];
  const float* init_h_mu = (const float*)d_in[9];
  float* dout = (float*)d_out;

  char* ws = (char*)d_ws;
  unsigned short* z_bf  = (unsigned short*)(ws);                      //  4,194,304 B
  unsigned short* Wu    = (unsigned short*)(ws + 4194304u);           //    589,824 B
  unsigned short* Wp    = (unsigned short*)(ws + 4784128u);           //    524,288 B
  unsigned short* Wdzp  = (unsigned short*)(ws + 5308416u);           //    131,072 B
  unsigned short* dinit = (unsigned short*)(ws + 5439488u);           //     32,768 B
  unsigned short* dcomm = (unsigned short*)(ws + 5472256u);           // 33,554,432 B (1024 slots)

  prep_ring_k<<<2048, 256, 0, stream>>>((uint4*)dcomm);
  prep_misc_k<<<1024, 256, 0, stream>>>(A, noise, Wd, Wz, Wdz, Whd, init_h,
                                        z_bf, Wu, Wp, Wdzp, dinit);
  wnll_k     <<<1,    256, 0, stream>>>(init_h, init_h_mu, dout);
  gemm_u_k   <<<1024, 256, 0, stream>>>(hd, z_bf, Wu, bias, dout);
  recur_k    <<<4,    512, 0, stream>>>(dout, init_h, Wp, dinit, dcomm);
  gemm_p_k   <<<256,  256, 0, stream>>>(dout, Wdzp, A, dout);
}

// Round 9
// 4652.876 us; speedup vs baseline: 2.9162x; 2.9162x over previous
//
#include <hip/hip_runtime.h>

typedef float f32x4  __attribute__((ext_vector_type(4)));
typedef float f32x16 __attribute__((ext_vector_type(16)));
typedef short short8 __attribute__((ext_vector_type(8)));
typedef int   intx4  __attribute__((ext_vector_type(4)));

#define TT 1024
#define DD 512
#define BTD (32u*1024u*512u)
#define SLOT_SH 16384      // shorts per slot (32KB); 1024 slots, written once each
#define SENTD  0xFF80FF80u

__device__ __forceinline__ unsigned short f2bf(float f){
  unsigned int u = __float_as_uint(f);
  u += 0x7FFFu + ((u >> 16) & 1u);          // round-to-nearest-even
  return (unsigned short)(u >> 16);
}
__device__ __forceinline__ float bf2f(unsigned short s){
  return __uint_as_float(((unsigned)s) << 16);
}
__device__ __forceinline__ float fast_tanh(float x){
  float ax = fabsf(x);
  float e  = __expf(2.0f*ax);
  float r  = 1.0f - 2.0f/(e + 1.0f);
  return x < 0.f ? -r : r;
}
__device__ __forceinline__ unsigned umaxu(unsigned a, unsigned b){ return a > b ? a : b; }

// ---------------- prep: sentinel-fill the 32MB ring ----------------
__global__ void prep_ring_k(uint4* __restrict__ p){
  const size_t n = (size_t)TT * SLOT_SH / 8;
  uint4 s = make_uint4(SENTD, SENTD, SENTD, SENTD);
  for (size_t i = blockIdx.x*(size_t)blockDim.x + threadIdx.x; i < n;
       i += (size_t)gridDim.x*blockDim.x)
    p[i] = s;
}

// ---------------- prep: z, packed weights, d_init (fragment layout) ----------------
__global__ void prep_misc_k(const float* __restrict__ A, const float* __restrict__ noise,
                            const float* __restrict__ Wd, const float* __restrict__ Wz,
                            const float* __restrict__ Wdz, const float* __restrict__ Whd,
                            const float* __restrict__ init_h,
                            unsigned short* __restrict__ zbf, unsigned short* __restrict__ Wu,
                            unsigned short* __restrict__ Wp, unsigned short* __restrict__ Wdzp,
                            unsigned short* __restrict__ dinit){
  const unsigned NZ = 2097152u, NWU = 294912u, NWP = 262144u, NWZ = 65536u, ND = 16384u;
  const unsigned NT = NZ + NWU + NWP + NWZ + ND;
  for (unsigned i = blockIdx.x*blockDim.x + threadIdx.x; i < NT; i += gridDim.x*blockDim.x){
    if (i < NZ){                                   // z = tanh(mu_in_q) + noise*exp(ln_q)
      unsigned m = i >> 6, zi = i & 63u;
      float muin = A[(size_t)m*128u + zi];
      float ln   = A[(size_t)m*128u + 64u + zi];
      zbf[i] = f2bf(fast_tanh(muin) + noise[i]*__expf(ln));
    } else if (i < NZ+NWU){                        // Wu[c][kk]: [Whd | Wz], [512][576]
      unsigned j = i - NZ;
      unsigned c = j / 576u, kk = j - c*576u;
      float v = (kk < 512u) ? Whd[(size_t)c*512u + kk] : Wz[(size_t)c*64u + (kk-512u)];
      Wu[j] = f2bf(v);
    } else if (i < NZ+NWU+NWP){                    // Wp[c][k] = Wd, [512][512]
      unsigned j = i - (NZ+NWU);
      Wp[j] = f2bf(Wd[j]);
    } else if (i < NZ+NWU+NWP+NWZ){                // Wdzp = bf16(Wdz), [128][512]
      unsigned j = i - (NZ+NWU+NWP);
      Wdzp[j] = f2bf(Wdz[j]);
    } else {                                       // d_{-1} = tanh(init_h), fragment layout
      unsigned j = i - (NZ+NWU+NWP+NWZ);
      unsigned b = j >> 9, c = j & 511u;
      unsigned idx = ((c>>4)<<9) + (((c>>3)&1u)<<8) + (b<<3) + (c&7u);
      dinit[idx] = f2bf(fast_tanh(init_h[j]));
    }
  }
}

// ---------------- wnll_init_h -> d_out[BTD] ----------------
__global__ void wnll_k(const float* __restrict__ init_h, const float* __restrict__ mu,
                       float* __restrict__ dout){
  __shared__ float red[256];
  float s = 0.f;
  for (unsigned i = threadIdx.x; i < 16384u; i += 256u){
    float x = init_h[i] - mu[i & 511u];
    s += 0.5f*x*x;
  }
  red[threadIdx.x] = s; __syncthreads();
  for (int st = 128; st > 0; st >>= 1){
    if ((int)threadIdx.x < st) red[threadIdx.x] += red[threadIdx.x + st];
    __syncthreads();
  }
  if (threadIdx.x == 0){
    float nll = (red[0] + 16384.0f*0.91893853320467274f) / 512.0f;
    dout[(size_t)BTD] = 1e-3f * nll;
  }
}

// ---------------- U = (X @ Wu^T + bias)/tau  into d_out (f32) ----------------
__global__ __launch_bounds__(256) void gemm_u_k(
    const float* __restrict__ hd,             // [32768][512] f32
    const unsigned short* __restrict__ Xz,    // [32768][64]  bf16
    const unsigned short* __restrict__ Wu,    // [512][576]   bf16
    const float* __restrict__ bias,
    float* __restrict__ dout)
{
  __shared__ __align__(16) unsigned short Xs[128][40];
  __shared__ __align__(16) unsigned short Ws[128][40];
  const int bm = blockIdx.x >> 2;
  const int bn = blockIdx.x & 3;
  const int tid = threadIdx.x;
  const int lane = tid & 63;
  const int wv = tid >> 6;
  const int m0 = (wv >> 1) * 64, c0 = (wv & 1) * 64;
  f32x4 acc[4][4];
  #pragma unroll
  for (int i=0;i<4;++i)
    #pragma unroll
    for (int j=0;j<4;++j)
      #pragma unroll
      for (int r=0;r<4;++r) acc[i][j][r] = 0.f;

  const int sm = tid >> 1;
  const int sk = (tid & 1) * 16;
  for (int kt = 0; kt < 18; ++kt){
    __syncthreads();
    {
      int mg = bm*128 + sm;
      if (kt < 16){
        const float* src = hd + (size_t)mg*512u + (unsigned)(kt*32 + sk);
        uint2 o[4];
        #pragma unroll
        for (int q=0;q<4;++q){
          f32x4 v = *reinterpret_cast<const f32x4*>(src + 4*q);
          o[q].x = (unsigned)f2bf(v[0]) | ((unsigned)f2bf(v[1])<<16);
          o[q].y = (unsigned)f2bf(v[2]) | ((unsigned)f2bf(v[3])<<16);
        }
        *reinterpret_cast<uint4*>(&Xs[sm][sk])   = make_uint4(o[0].x,o[0].y,o[1].x,o[1].y);
        *reinterpret_cast<uint4*>(&Xs[sm][sk+8]) = make_uint4(o[2].x,o[2].y,o[3].x,o[3].y);
      } else {
        const unsigned short* src = Xz + (size_t)mg*64u + (unsigned)((kt-16)*32 + sk);
        uint4 v0 = *reinterpret_cast<const uint4*>(src);
        uint4 v1 = *reinterpret_cast<const uint4*>(src + 8);
        *reinterpret_cast<uint4*>(&Xs[sm][sk])   = v0;
        *reinterpret_cast<uint4*>(&Xs[sm][sk+8]) = v1;
      }
      int cg = bn*128 + sm;
      const unsigned short* wsrc = Wu + (size_t)cg*576u + (unsigned)(kt*32 + sk);
      uint4 w0 = *reinterpret_cast<const uint4*>(wsrc);
      uint4 w1 = *reinterpret_cast<const uint4*>(wsrc + 8);
      *reinterpret_cast<uint4*>(&Ws[sm][sk])   = w0;
      *reinterpret_cast<uint4*>(&Ws[sm][sk+8]) = w1;
    }
    __syncthreads();
    short8 af[4], bf[4];
    #pragma unroll
    for (int i=0;i<4;++i)
      af[i] = *reinterpret_cast<const short8*>(&Xs[m0 + i*16 + (lane&15)][(lane>>4)*8]);
    #pragma unroll
    for (int j=0;j<4;++j)
      bf[j] = *reinterpret_cast<const short8*>(&Ws[c0 + j*16 + (lane&15)][(lane>>4)*8]);
    #pragma unroll
    for (int i=0;i<4;++i)
      #pragma unroll
      for (int j=0;j<4;++j)
        acc[i][j] = __builtin_amdgcn_mfma_f32_16x16x32_bf16(af[i], bf[j], acc[i][j], 0, 0, 0);
  }
  #pragma unroll
  for (int j=0;j<4;++j){
    int cg = bn*128 + c0 + j*16 + (lane&15);
    float bia  = bias[cg];
    float itau = (cg < 256) ? 0.25f : 0.5f;
    #pragma unroll
    for (int i=0;i<4;++i){
      int mbase = bm*128 + m0 + i*16 + (lane>>4)*4;
      #pragma unroll
      for (int r=0;r<4;++r)
        dout[(size_t)(mbase + r)*512u + cg] = (acc[i][j][r] + bia) * itau;
    }
  }
}

// ---------------- persistent serial recurrence: sentinel-sync, write-once ring ----------------
// grid = 20 WGs x 256.  WG 0..15 (wave 0): D-column workers, 32 cols each.
// WG 16..19 (4 waves): d_seq writers, 16 wave-portions of 2KB per slot.
// Ring: 1024 slots (one per step), each written EXACTLY once -> monotone, no
// reuse, deadlock-free. Valid data dwords < 0xC0000000u (bf16 tanh outputs);
// sentinel 0xFF80FF80. All ring traffic sc0 sc1.
// Round-9 change: per-CHUNK validate + immediate MFMA (4 interleaved acc
// chains); retries re-issue ONLY pending chunks, overlapping compute.
__global__ __launch_bounds__(256,1) void recur_k(
    float* __restrict__ dout, const float* __restrict__ init_h,
    const unsigned short* __restrict__ Wp, const unsigned short* __restrict__ dinit,
    unsigned short* __restrict__ dcomm)
{
  __shared__ __align__(16) unsigned short tl[32][40];   // transpose block
  const int wg = blockIdx.x;

  // ================= writer WGs (16 waves across 4 WGs) =================
  if (wg >= 16){
    const int tid  = threadIdx.x;
    const int lane = tid & 63;
    const int wid  = (wg - 16)*4 + (tid >> 6);    // 0..15, owns 2KB of each slot
    const int b    = lane & 31;
    const int cb0  = wid*32 + (lane>>5)*8;
    for (int t = 0; t < TT; ++t){
      const char* base = (const char*)dcomm + (size_t)t*32768 + wid*2048 + lane*16;
      intx4 q0, q1;
      for (;;){
        asm volatile(
          "global_load_dwordx4 %0, %2, off sc0 sc1\n\t"
          "global_load_dwordx4 %1, %2, off offset:1024 sc0 sc1\n\t"
          "s_waitcnt vmcnt(0)"
          : "=&v"(q0), "=&v"(q1) : "v"(base) : "memory");
        unsigned mx = umaxu(umaxu(umaxu((unsigned)q0[0],(unsigned)q0[1]),
                                  umaxu((unsigned)q0[2],(unsigned)q0[3])),
                            umaxu(umaxu((unsigned)q1[0],(unsigned)q1[1]),
                                  umaxu((unsigned)q1[2],(unsigned)q1[3])));
        if (__all(mx < 0xC0000000u)) break;
      }
      __builtin_amdgcn_sched_barrier(0);
      float* drow = dout + ((size_t)b*TT + t)*DD;
      union { intx4 i; short8 s; } c0, c1; c0.i = q0; c1.i = q1;
      f32x4 o0, o1, o2, o3;
      #pragma unroll
      for (int e=0;e<4;++e){
        o0[e] = bf2f((unsigned short)c0.s[e]);
        o1[e] = bf2f((unsigned short)c0.s[4+e]);
        o2[e] = bf2f((unsigned short)c1.s[e]);
        o3[e] = bf2f((unsigned short)c1.s[4+e]);
      }
      *reinterpret_cast<f32x4*>(drow + cb0)          = o0;
      *reinterpret_cast<f32x4*>(drow + cb0 + 4)      = o1;
      *reinterpret_cast<f32x4*>(drow + cb0 + 16)     = o2;
      *reinterpret_cast<f32x4*>(drow + cb0 + 16 + 4) = o3;
    }
    return;
  }

  // ================= worker WGs (wave 0 only) =================
  if (threadIdx.x >= 64) return;
  const int lane = threadIdx.x;
  const int pc    = wg*32 + (lane & 31);      // D column 0..511
  const int khalf = (lane >> 5) * 8;
  const int bof   = (lane >> 5) * 4;

  short8 wfrag[32];
  #pragma unroll
  for (int kc = 0; kc < 32; ++kc)
    wfrag[kc] = *reinterpret_cast<const short8*>(Wp + (size_t)pc*512u + (unsigned)(kc*16 + khalf));

  const float dec  = (pc < 256) ? 0.75f : 0.5f;
  const float itau = (pc < 256) ? 0.25f : 0.5f;

  float h[16];
  #pragma unroll
  for (int r=0;r<16;++r){
    int b = (r&3) + 8*(r>>2) + bof;
    h[r] = init_h[b*512 + pc];
  }
  float u[16];
  #pragma unroll
  for (int r=0;r<16;++r){
    int b = (r&3) + 8*(r>>2) + bof;
    u[r] = dout[((size_t)b*TT + 0)*DD + pc];
  }

  union CV { intx4 i; short8 s; };

  for (int t = 0; t < TT; ++t){
    const char* gbase = (t == 0)
        ? (const char*)dinit
        : (const char*)dcomm + (size_t)(t-1)*32768;
    const char* base = gbase + lane*16;

    // issue all 32 chunk loads (chunk j = 1KB written by one producer wave)
    intx4 fi[32];
    #pragma unroll
    for (int g = 0; g < 8; ++g){
      const char* bp = base + g*4096;
      asm volatile(
        "global_load_dwordx4 %0, %4, off sc0 sc1\n\t"
        "global_load_dwordx4 %1, %4, off offset:1024 sc0 sc1\n\t"
        "global_load_dwordx4 %2, %4, off offset:2048 sc0 sc1\n\t"
        "global_load_dwordx4 %3, %4, off offset:3072 sc0 sc1"
        : "=&v"(fi[4*g]), "=&v"(fi[4*g+1]), "=&v"(fi[4*g+2]), "=&v"(fi[4*g+3])
        : "v"(bp) : "memory");
    }
    asm volatile("s_waitcnt vmcnt(0)" ::: "memory");
    __builtin_amdgcn_sched_barrier(0);

    // per-chunk validate + immediate MFMA into 4 interleaved chains
    f32x16 acc0, acc1, acc2, acc3;
    #pragma unroll
    for (int q=0;q<16;++q){ acc0[q]=0.f; acc1[q]=0.f; acc2[q]=0.f; acc3[q]=0.f; }
    unsigned pend = 0u;
    #pragma unroll
    for (int j=0;j<32;++j){
      unsigned mx = umaxu(umaxu((unsigned)fi[j][0],(unsigned)fi[j][1]),
                          umaxu((unsigned)fi[j][2],(unsigned)fi[j][3]));
      if (__all(mx < 0xC0000000u)){
        CV cv; cv.i = fi[j];
        if      ((j&3)==0) acc0 = __builtin_amdgcn_mfma_f32_32x32x16_bf16(cv.s, wfrag[j], acc0, 0,0,0);
        else if ((j&3)==1) acc1 = __builtin_amdgcn_mfma_f32_32x32x16_bf16(cv.s, wfrag[j], acc1, 0,0,0);
        else if ((j&3)==2) acc2 = __builtin_amdgcn_mfma_f32_32x32x16_bf16(cv.s, wfrag[j], acc2, 0,0,0);
        else               acc3 = __builtin_amdgcn_mfma_f32_32x32x16_bf16(cv.s, wfrag[j], acc3, 0,0,0);
      } else pend |= (1u << j);
    }
    // retry ONLY pending chunks; MFMA of arrived chunks overlaps the waits
    while (pend){
      #pragma unroll
      for (int j=0;j<32;++j){
        if (pend & (1u << j)){
          const char* bp = base + j*1024;
          asm volatile("global_load_dwordx4 %0, %1, off sc0 sc1"
                       : "=&v"(fi[j]) : "v"(bp) : "memory");
        }
      }
      asm volatile("s_waitcnt vmcnt(0)" ::: "memory");
      __builtin_amdgcn_sched_barrier(0);
      #pragma unroll
      for (int j=0;j<32;++j){
        if (pend & (1u << j)){
          unsigned mx = umaxu(umaxu((unsigned)fi[j][0],(unsigned)fi[j][1]),
                              umaxu((unsigned)fi[j][2],(unsigned)fi[j][3]));
          if (__all(mx < 0xC0000000u)){
            CV cv; cv.i = fi[j];
            if      ((j&3)==0) acc0 = __builtin_amdgcn_mfma_f32_32x32x16_bf16(cv.s, wfrag[j], acc0, 0,0,0);
            else if ((j&3)==1) acc1 = __builtin_amdgcn_mfma_f32_32x32x16_bf16(cv.s, wfrag[j], acc1, 0,0,0);
            else if ((j&3)==2) acc2 = __builtin_amdgcn_mfma_f32_32x32x16_bf16(cv.s, wfrag[j], acc2, 0,0,0);
            else               acc3 = __builtin_amdgcn_mfma_f32_32x32x16_bf16(cv.s, wfrag[j], acc3, 0,0,0);
            pend &= ~(1u << j);
          }
        }
      }
    }

    // prefetch next-step U (issued after all retry drains; completes during
    // tanh/transpose/store and the next step's gather latency)
    float un[16];
    if (t+1 < TT){
      #pragma unroll
      for (int r=0;r<16;++r){
        int b = (r&3) + 8*(r>>2) + bof;
        un[r] = dout[((size_t)b*TT + (t+1))*DD + pc];
      }
    }

    // h update + tanh
    float dv[16];
    #pragma unroll
    for (int r=0;r<16;++r){
      float P = acc0[r] + acc1[r] + acc2[r] + acc3[r];
      h[r]  = dec*h[r] + P*itau + u[r];
      dv[r] = fast_tanh(h[r]);
    }
    // in-wave transpose via LDS: tl[batch][local col]
    #pragma unroll
    for (int r=0;r<16;++r){
      int b = (r&3) + 8*(r>>2) + bof;
      tl[b][lane & 31] = f2bf(dv[r]);
    }
    // two coalesced b128 uncached stores into fragment-layout slot; fire-and-forget
    {
      unsigned short* ds = dcomm + (size_t)t*SLOT_SH + (2*wg)*512 + lane*8;
      short8 s0 = *reinterpret_cast<const short8*>(&tl[lane & 31][khalf]);
      short8 s1 = *reinterpret_cast<const short8*>(&tl[lane & 31][16 + khalf]);
      asm volatile("global_store_dwordx4 %0, %2, off sc0 sc1\n\t"
                   "global_store_dwordx4 %1, %3, off sc0 sc1"
                   :: "v"(ds), "v"(ds + 512), "v"(s0), "v"(s1) : "memory");
    }
    if (t+1 < TT){
      #pragma unroll
      for (int r=0;r<16;++r) u[r] = un[r];
    }
  }
}

// ---------------- epilogue: prior_in = d_shifted @ Wdz^T, fused KL -> atomicAdd ----------------
__global__ __launch_bounds__(256) void gemm_p_k(
    const float* __restrict__ dseq,           // dout: [32][1024][512] f32
    const unsigned short* __restrict__ Wdzp,  // [128][512] bf16
    const float* __restrict__ A,              // [32768][128] f32
    float* __restrict__ dout)
{
  __shared__ __align__(16) unsigned short Xs[128][40];
  __shared__ __align__(16) unsigned short Ws[128][40];
  __shared__ float Ls[128][128];
  __shared__ float red[256];
  const int bm = blockIdx.x;
  const int tid = threadIdx.x;
  const int lane = tid & 63;
  const int wv = tid >> 6;
  const int m0 = (wv >> 1) * 64, c0 = (wv & 1) * 64;
  f32x4 acc[4][4];
  #pragma unroll
  for (int i=0;i<4;++i)
    #pragma unroll
    for (int j=0;j<4;++j)
      #pragma unroll
      for (int r=0;r<4;++r) acc[i][j][r] = 0.f;

  const int sm = tid >> 1;
  const int sk = (tid & 1) * 16;
  for (int kt = 0; kt < 16; ++kt){
    __syncthreads();
    {
      int mg = bm*128 + sm;
      int ttm = mg & 1023;
      int srow = (ttm == 0) ? mg : (mg - 1);       // d[b][t-1]; t==0 rows overridden in KL
      const float* src = dseq + (size_t)srow*512u + (unsigned)(kt*32 + sk);
      uint2 o[4];
      #pragma unroll
      for (int q=0;q<4;++q){
        f32x4 v = *reinterpret_cast<const f32x4*>(src + 4*q);
        o[q].x = (unsigned)f2bf(v[0]) | ((unsigned)f2bf(v[1])<<16);
        o[q].y = (unsigned)f2bf(v[2]) | ((unsigned)f2bf(v[3])<<16);
      }
      *reinterpret_cast<uint4*>(&Xs[sm][sk])   = make_uint4(o[0].x,o[0].y,o[1].x,o[1].y);
      *reinterpret_cast<uint4*>(&Xs[sm][sk+8]) = make_uint4(o[2].x,o[2].y,o[3].x,o[3].y);
      const unsigned short* wsrc = Wdzp + (size_t)sm*512u + (unsigned)(kt*32 + sk);
      uint4 w0 = *reinterpret_cast<const uint4*>(wsrc);
      uint4 w1 = *reinterpret_cast<const uint4*>(wsrc + 8);
      *reinterpret_cast<uint4*>(&Ws[sm][sk])   = w0;
      *reinterpret_cast<uint4*>(&Ws[sm][sk+8]) = w1;
    }
    __syncthreads();
    short8 af[4], bf[4];
    #pragma unroll
    for (int i=0;i<4;++i)
      af[i] = *reinterpret_cast<const short8*>(&Xs[m0 + i*16 + (lane&15)][(lane>>4)*8]);
    #pragma unroll
    for (int j=0;j<4;++j)
      bf[j] = *reinterpret_cast<const short8*>(&Ws[c0 + j*16 + (lane&15)][(lane>>4)*8]);
    #pragma unroll
    for (int i=0;i<4;++i)
      #pragma unroll
      for (int j=0;j<4;++j)
        acc[i][j] = __builtin_amdgcn_mfma_f32_16x16x32_bf16(af[i], bf[j], acc[i][j], 0, 0, 0);
  }
  #pragma unroll
  for (int j=0;j<4;++j){
    int cc = c0 + j*16 + (lane&15);
    #pragma unroll
    for (int i=0;i<4;++i){
      int mm = m0 + i*16 + (lane>>4)*4;
      #pragma unroll
      for (int r=0;r<4;++r)
        Ls[mm + r][cc] = acc[i][j][r];
    }
  }
  __syncthreads();
  float ks = 0.f;
  const int z = tid & 63;
  for (int ml = (tid >> 6); ml < 128; ml += 4){
    int mg = bm*128 + ml;
    int ttm = mg & 1023;
    const float* ap = A + (size_t)mg*128u;
    float mq = fast_tanh(ap[z]);
    float sq = __expf(ap[64 + z]);
    float mp = (ttm == 0) ? 0.f : fast_tanh(Ls[ml][z]);
    float sp = (ttm == 0) ? 1.f : __expf(Ls[ml][64 + z]);
    float dm = mq - mp;
    ks += __logf(sp + 1e-6f) - __logf(sq + 1e-6f) - 0.5f
        + 0.5f*(dm*dm + sq*sq)/(sp*sp + 1e-6f);
  }
  red[tid] = ks; __syncthreads();
  for (int st = 128; st > 0; st >>= 1){
    if (tid < st) red[tid] += red[tid + st];
    __syncthreads();
  }
  if (tid == 0) atomicAdd(dout + (size_t)BTD, red[0] * (1e-3f/64.f));
}

extern "C" void kernel_launch(void* const* d_in, const int* in_sizes, int n_in,
                              void* d_out, int out_size, void* d_ws, size_t ws_size,
                              hipStream_t stream){
  const float* hd        = (const float*)d_in[0];
  const float* A         = (const float*)d_in[1];
  const float* noise     = (const float*)d_in[2];
  const float* Wd        = (const float*)d_in[3];
  const float* Wz        = (const float*)d_in[4];
  const float* Wdz       = (const float*)d_in[5];
  const float* Whd       = (const float*)d_in[6];
  const float* bias      = (const float*)d_in[7];
  const float* init_h    = (const float*)d_in[8];
  const float* init_h_mu = (const float*)d_in[9];
  float* dout = (float*)d_out;

  char* ws = (char*)d_ws;
  unsigned short* z_bf  = (unsigned short*)(ws);                      //  4,194,304 B
  unsigned short* Wu    = (unsigned short*)(ws + 4194304u);           //    589,824 B
  unsigned short* Wp    = (unsigned short*)(ws + 4784128u);           //    524,288 B
  unsigned short* Wdzp  = (unsigned short*)(ws + 5308416u);           //    131,072 B
  unsigned short* dinit = (unsigned short*)(ws + 5439488u);           //     32,768 B
  unsigned short* dcomm = (unsigned short*)(ws + 5472256u);           // 33,554,432 B (1024 slots)

  prep_ring_k<<<2048, 256, 0, stream>>>((uint4*)dcomm);
  prep_misc_k<<<1024, 256, 0, stream>>>(A, noise, Wd, Wz, Wdz, Whd, init_h,
                                        z_bf, Wu, Wp, Wdzp, dinit);
  wnll_k     <<<1,    256, 0, stream>>>(init_h, init_h_mu, dout);
  gemm_u_k   <<<1024, 256, 0, stream>>>(hd, z_bf, Wu, bias, dout);
  recur_k    <<<20,   256, 0, stream>>>(dout, init_h, Wp, dinit, dcomm);
  gemm_p_k   <<<256,  256, 0, stream>>>(dout, Wdzp, A, dout);
}

// Round 10
// 2982.566 us; speedup vs baseline: 4.5494x; 1.5600x over previous
//
#include <hip/hip_runtime.h>

typedef float f32x4  __attribute__((ext_vector_type(4)));
typedef float f32x16 __attribute__((ext_vector_type(16)));
typedef short short8 __attribute__((ext_vector_type(8)));
typedef int   intx4  __attribute__((ext_vector_type(4)));

#define TT 1024
#define DD 512
#define BTD (32u*1024u*512u)
#define SLOT_SH 16384      // shorts per slot (32KB); 1024 slots, written once each
#define SENTD  0xFF80FF80u

__device__ __forceinline__ unsigned short f2bf(float f){
  unsigned int u = __float_as_uint(f);
  u += 0x7FFFu + ((u >> 16) & 1u);          // round-to-nearest-even
  return (unsigned short)(u >> 16);
}
__device__ __forceinline__ float bf2f(unsigned short s){
  return __uint_as_float(((unsigned)s) << 16);
}
__device__ __forceinline__ float fast_tanh(float x){
  float ax = fabsf(x);
  float e  = __expf(2.0f*ax);
  float r  = 1.0f - 2.0f/(e + 1.0f);
  return x < 0.f ? -r : r;
}
__device__ __forceinline__ unsigned umaxu(unsigned a, unsigned b){ return a > b ? a : b; }

// ---------------- prep: sentinel-fill the 32MB ring ----------------
__global__ void prep_ring_k(uint4* __restrict__ p){
  const size_t n = (size_t)TT * SLOT_SH / 8;
  uint4 s = make_uint4(SENTD, SENTD, SENTD, SENTD);
  for (size_t i = blockIdx.x*(size_t)blockDim.x + threadIdx.x; i < n;
       i += (size_t)gridDim.x*blockDim.x)
    p[i] = s;
}

// ---------------- prep: z, packed weights, d_init (fragment layout) ----------------
__global__ void prep_misc_k(const float* __restrict__ A, const float* __restrict__ noise,
                            const float* __restrict__ Wd, const float* __restrict__ Wz,
                            const float* __restrict__ Wdz, const float* __restrict__ Whd,
                            const float* __restrict__ init_h,
                            unsigned short* __restrict__ zbf, unsigned short* __restrict__ Wu,
                            unsigned short* __restrict__ Wp, unsigned short* __restrict__ Wdzp,
                            unsigned short* __restrict__ dinit){
  const unsigned NZ = 2097152u, NWU = 294912u, NWP = 262144u, NWZ = 65536u, ND = 16384u;
  const unsigned NT = NZ + NWU + NWP + NWZ + ND;
  for (unsigned i = blockIdx.x*blockDim.x + threadIdx.x; i < NT; i += gridDim.x*blockDim.x){
    if (i < NZ){                                   // z = tanh(mu_in_q) + noise*exp(ln_q)
      unsigned m = i >> 6, zi = i & 63u;
      float muin = A[(size_t)m*128u + zi];
      float ln   = A[(size_t)m*128u + 64u + zi];
      zbf[i] = f2bf(fast_tanh(muin) + noise[i]*__expf(ln));
    } else if (i < NZ+NWU){                        // Wu[c][kk]: [Whd | Wz], [512][576]
      unsigned j = i - NZ;
      unsigned c = j / 576u, kk = j - c*576u;
      float v = (kk < 512u) ? Whd[(size_t)c*512u + kk] : Wz[(size_t)c*64u + (kk-512u)];
      Wu[j] = f2bf(v);
    } else if (i < NZ+NWU+NWP){                    // Wp[c][k] = Wd, [512][512]
      unsigned j = i - (NZ+NWU);
      Wp[j] = f2bf(Wd[j]);
    } else if (i < NZ+NWU+NWP+NWZ){                // Wdzp = bf16(Wdz), [128][512]
      unsigned j = i - (NZ+NWU+NWP);
      Wdzp[j] = f2bf(Wdz[j]);
    } else {                                       // d_{-1} = tanh(init_h), fragment layout
      unsigned j = i - (NZ+NWU+NWP+NWZ);
      unsigned b = j >> 9, c = j & 511u;
      unsigned idx = ((c>>4)<<9) + (((c>>3)&1u)<<8) + (b<<3) + (c&7u);
      dinit[idx] = f2bf(fast_tanh(init_h[j]));
    }
  }
}

// ---------------- wnll_init_h -> d_out[BTD] ----------------
__global__ void wnll_k(const float* __restrict__ init_h, const float* __restrict__ mu,
                       float* __restrict__ dout){
  __shared__ float red[256];
  float s = 0.f;
  for (unsigned i = threadIdx.x; i < 16384u; i += 256u){
    float x = init_h[i] - mu[i & 511u];
    s += 0.5f*x*x;
  }
  red[threadIdx.x] = s; __syncthreads();
  for (int st = 128; st > 0; st >>= 1){
    if ((int)threadIdx.x < st) red[threadIdx.x] += red[threadIdx.x + st];
    __syncthreads();
  }
  if (threadIdx.x == 0){
    float nll = (red[0] + 16384.0f*0.91893853320467274f) / 512.0f;
    dout[(size_t)BTD] = 1e-3f * nll;
  }
}

// ---------------- U = (X @ Wu^T + bias)/tau  into d_out (f32) ----------------
__global__ __launch_bounds__(256) void gemm_u_k(
    const float* __restrict__ hd,             // [32768][512] f32
    const unsigned short* __restrict__ Xz,    // [32768][64]  bf16
    const unsigned short* __restrict__ Wu,    // [512][576]   bf16
    const float* __restrict__ bias,
    float* __restrict__ dout)
{
  __shared__ __align__(16) unsigned short Xs[128][40];
  __shared__ __align__(16) unsigned short Ws[128][40];
  const int bm = blockIdx.x >> 2;
  const int bn = blockIdx.x & 3;
  const int tid = threadIdx.x;
  const int lane = tid & 63;
  const int wv = tid >> 6;
  const int m0 = (wv >> 1) * 64, c0 = (wv & 1) * 64;
  f32x4 acc[4][4];
  #pragma unroll
  for (int i=0;i<4;++i)
    #pragma unroll
    for (int j=0;j<4;++j)
      #pragma unroll
      for (int r=0;r<4;++r) acc[i][j][r] = 0.f;

  const int sm = tid >> 1;
  const int sk = (tid & 1) * 16;
  for (int kt = 0; kt < 18; ++kt){
    __syncthreads();
    {
      int mg = bm*128 + sm;
      if (kt < 16){
        const float* src = hd + (size_t)mg*512u + (unsigned)(kt*32 + sk);
        uint2 o[4];
        #pragma unroll
        for (int q=0;q<4;++q){
          f32x4 v = *reinterpret_cast<const f32x4*>(src + 4*q);
          o[q].x = (unsigned)f2bf(v[0]) | ((unsigned)f2bf(v[1])<<16);
          o[q].y = (unsigned)f2bf(v[2]) | ((unsigned)f2bf(v[3])<<16);
        }
        *reinterpret_cast<uint4*>(&Xs[sm][sk])   = make_uint4(o[0].x,o[0].y,o[1].x,o[1].y);
        *reinterpret_cast<uint4*>(&Xs[sm][sk+8]) = make_uint4(o[2].x,o[2].y,o[3].x,o[3].y);
      } else {
        const unsigned short* src = Xz + (size_t)mg*64u + (unsigned)((kt-16)*32 + sk);
        uint4 v0 = *reinterpret_cast<const uint4*>(src);
        uint4 v1 = *reinterpret_cast<const uint4*>(src + 8);
        *reinterpret_cast<uint4*>(&Xs[sm][sk])   = v0;
        *reinterpret_cast<uint4*>(&Xs[sm][sk+8]) = v1;
      }
      int cg = bn*128 + sm;
      const unsigned short* wsrc = Wu + (size_t)cg*576u + (unsigned)(kt*32 + sk);
      uint4 w0 = *reinterpret_cast<const uint4*>(wsrc);
      uint4 w1 = *reinterpret_cast<const uint4*>(wsrc + 8);
      *reinterpret_cast<uint4*>(&Ws[sm][sk])   = w0;
      *reinterpret_cast<uint4*>(&Ws[sm][sk+8]) = w1;
    }
    __syncthreads();
    short8 af[4], bf[4];
    #pragma unroll
    for (int i=0;i<4;++i)
      af[i] = *reinterpret_cast<const short8*>(&Xs[m0 + i*16 + (lane&15)][(lane>>4)*8]);
    #pragma unroll
    for (int j=0;j<4;++j)
      bf[j] = *reinterpret_cast<const short8*>(&Ws[c0 + j*16 + (lane&15)][(lane>>4)*8]);
    #pragma unroll
    for (int i=0;i<4;++i)
      #pragma unroll
      for (int j=0;j<4;++j)
        acc[i][j] = __builtin_amdgcn_mfma_f32_16x16x32_bf16(af[i], bf[j], acc[i][j], 0, 0, 0);
  }
  #pragma unroll
  for (int j=0;j<4;++j){
    int cg = bn*128 + c0 + j*16 + (lane&15);
    float bia  = bias[cg];
    float itau = (cg < 256) ? 0.25f : 0.5f;
    #pragma unroll
    for (int i=0;i<4;++i){
      int mbase = bm*128 + m0 + i*16 + (lane>>4)*4;
      #pragma unroll
      for (int r=0;r<4;++r)
        dout[(size_t)(mbase + r)*512u + cg] = (acc[i][j][r] + bia) * itau;
    }
  }
}

// ---------------- persistent serial recurrence: sentinel-sync, write-once ring ----------------
// grid = 20 WGs x 256.  WG 0..15 (wave 0): D-column workers, 32 cols each.
// WG 16..19 (4 waves): d_seq writers, 16 wave-portions of 2KB per slot.
// Ring: 1024 slots (one per step), each written EXACTLY once -> monotone, no
// reuse, deadlock-free. Valid data dwords < 0xC0000000u (bf16 tanh outputs);
// sentinel 0xFF80FF80. All ring traffic sc0 sc1.
// Round-10: depth-2 speculative gather pipeline. Write-once data makes the
// WAW race on fi benign (a later sample can only overwrite with identical
// final data). Sample k+1 is issued before validating sample k, so the
// sampling interval is ~issue+validate instead of a full L3 round trip.
__global__ __launch_bounds__(256,1) void recur_k(
    float* __restrict__ dout, const float* __restrict__ init_h,
    const unsigned short* __restrict__ Wp, const unsigned short* __restrict__ dinit,
    unsigned short* __restrict__ dcomm)
{
  __shared__ __align__(16) unsigned short tl[32][40];   // transpose block
  const int wg = blockIdx.x;

  // ================= writer WGs (16 waves across 4 WGs) =================
  if (wg >= 16){
    const int tid  = threadIdx.x;
    const int lane = tid & 63;
    const int wid  = (wg - 16)*4 + (tid >> 6);    // 0..15, owns 2KB of each slot
    const int b    = lane & 31;
    const int cb0  = wid*32 + (lane>>5)*8;
    for (int t = 0; t < TT; ++t){
      const char* base = (const char*)dcomm + (size_t)t*32768 + wid*2048 + lane*16;
      intx4 q0, q1;
      for (;;){
        asm volatile(
          "global_load_dwordx4 %0, %2, off sc0 sc1\n\t"
          "global_load_dwordx4 %1, %2, off offset:1024 sc0 sc1\n\t"
          "s_waitcnt vmcnt(0)"
          : "=&v"(q0), "=&v"(q1) : "v"(base) : "memory");
        unsigned mx = umaxu(umaxu(umaxu((unsigned)q0[0],(unsigned)q0[1]),
                                  umaxu((unsigned)q0[2],(unsigned)q0[3])),
                            umaxu(umaxu((unsigned)q1[0],(unsigned)q1[1]),
                                  umaxu((unsigned)q1[2],(unsigned)q1[3])));
        if (__all(mx < 0xC0000000u)) break;
        __builtin_amdgcn_s_sleep(4);   // writers have unbounded slack: back off
      }
      __builtin_amdgcn_sched_barrier(0);
      float* drow = dout + ((size_t)b*TT + t)*DD;
      union { intx4 i; short8 s; } c0, c1; c0.i = q0; c1.i = q1;
      f32x4 o0, o1, o2, o3;
      #pragma unroll
      for (int e=0;e<4;++e){
        o0[e] = bf2f((unsigned short)c0.s[e]);
        o1[e] = bf2f((unsigned short)c0.s[4+e]);
        o2[e] = bf2f((unsigned short)c1.s[e]);
        o3[e] = bf2f((unsigned short)c1.s[4+e]);
      }
      *reinterpret_cast<f32x4*>(drow + cb0)          = o0;
      *reinterpret_cast<f32x4*>(drow + cb0 + 4)      = o1;
      *reinterpret_cast<f32x4*>(drow + cb0 + 16)     = o2;
      *reinterpret_cast<f32x4*>(drow + cb0 + 16 + 4) = o3;
    }
    return;
  }

  // ================= worker WGs (wave 0 only) =================
  if (threadIdx.x >= 64) return;
  const int lane = threadIdx.x;
  const int pc    = wg*32 + (lane & 31);      // D column 0..511
  const int khalf = (lane >> 5) * 8;
  const int bof   = (lane >> 5) * 4;

  short8 wfrag[32];
  #pragma unroll
  for (int kc = 0; kc < 32; ++kc)
    wfrag[kc] = *reinterpret_cast<const short8*>(Wp + (size_t)pc*512u + (unsigned)(kc*16 + khalf));

  const float dec  = (pc < 256) ? 0.75f : 0.5f;
  const float itau = (pc < 256) ? 0.25f : 0.5f;

  float h[16];
  #pragma unroll
  for (int r=0;r<16;++r){
    int b = (r&3) + 8*(r>>2) + bof;
    h[r] = init_h[b*512 + pc];
  }
  float u[16];
  #pragma unroll
  for (int r=0;r<16;++r){
    int b = (r&3) + 8*(r>>2) + bof;
    u[r] = dout[((size_t)b*TT + 0)*DD + pc];
  }

  union CV { intx4 i; short8 s; };

  for (int t = 0; t < TT; ++t){
    const char* gbase = (t == 0)
        ? (const char*)dinit
        : (const char*)dcomm + (size_t)(t-1)*32768;
    const char* base = gbase + lane*16;

    intx4 fi[32];
    // sample 1: fresh defs ("=&v")
    #pragma unroll
    for (int g = 0; g < 8; ++g){
      const char* bp = base + g*4096;
      asm volatile(
        "global_load_dwordx4 %0, %4, off sc0 sc1\n\t"
        "global_load_dwordx4 %1, %4, off offset:1024 sc0 sc1\n\t"
        "global_load_dwordx4 %2, %4, off offset:2048 sc0 sc1\n\t"
        "global_load_dwordx4 %3, %4, off offset:3072 sc0 sc1"
        : "=&v"(fi[4*g]), "=&v"(fi[4*g+1]), "=&v"(fi[4*g+2]), "=&v"(fi[4*g+3])
        : "v"(bp) : "memory");
    }
    // depth-2 standing pipeline: issue sample k+1 ("+v": ties to SAME regs),
    // wait for sample k (vmcnt(32)), validate; repeat until clean.
    for (;;){
      #pragma unroll
      for (int g = 0; g < 8; ++g){
        const char* bp = base + g*4096;
        asm volatile(
          "global_load_dwordx4 %0, %4, off sc0 sc1\n\t"
          "global_load_dwordx4 %1, %4, off offset:1024 sc0 sc1\n\t"
          "global_load_dwordx4 %2, %4, off offset:2048 sc0 sc1\n\t"
          "global_load_dwordx4 %3, %4, off offset:3072 sc0 sc1"
          : "+v"(fi[4*g]), "+v"(fi[4*g+1]), "+v"(fi[4*g+2]), "+v"(fi[4*g+3])
          : "v"(bp) : "memory");
      }
      asm volatile("s_waitcnt vmcnt(32)" ::: "memory");
      __builtin_amdgcn_sched_barrier(0);
      unsigned mx = 0u;
      #pragma unroll
      for (int j=0;j<32;++j){
        mx = umaxu(mx, umaxu(umaxu((unsigned)fi[j][0],(unsigned)fi[j][1]),
                             umaxu((unsigned)fi[j][2],(unsigned)fi[j][3])));
      }
      if (__all(mx < 0xC0000000u)) break;
    }
    // drain the in-flight sample (overwrites with identical write-once data)
    asm volatile("s_waitcnt vmcnt(0)" ::: "memory");
    __builtin_amdgcn_sched_barrier(0);

    // prefetch next-step U (cached; completes during MFMA/tanh/store)
    float un[16];
    if (t+1 < TT){
      #pragma unroll
      for (int r=0;r<16;++r){
        int b = (r&3) + 8*(r>>2) + bof;
        un[r] = dout[((size_t)b*TT + (t+1))*DD + pc];
      }
    }

    // P = d_{t-1} @ W_slice  (two interleaved MFMA chains — round-7 proven codegen)
    f32x16 acc0, acc1;
    #pragma unroll
    for (int q=0;q<16;++q){ acc0[q]=0.f; acc1[q]=0.f; }
    #pragma unroll
    for (int kc=0;kc<16;++kc){
      CV c0, c1; c0.i = fi[2*kc]; c1.i = fi[2*kc+1];
      acc0 = __builtin_amdgcn_mfma_f32_32x32x16_bf16(c0.s, wfrag[2*kc  ], acc0, 0, 0, 0);
      acc1 = __builtin_amdgcn_mfma_f32_32x32x16_bf16(c1.s, wfrag[2*kc+1], acc1, 0, 0, 0);
    }

    // h update + tanh
    float dv[16];
    #pragma unroll
    for (int r=0;r<16;++r){
      float P = acc0[r] + acc1[r];
      h[r]  = dec*h[r] + P*itau + u[r];
      dv[r] = fast_tanh(h[r]);
    }
    // in-wave transpose via LDS: tl[batch][local col]
    #pragma unroll
    for (int r=0;r<16;++r){
      int b = (r&3) + 8*(r>>2) + bof;
      tl[b][lane & 31] = f2bf(dv[r]);
    }
    // two coalesced b128 uncached stores into fragment-layout slot; fire-and-forget
    {
      unsigned short* ds = dcomm + (size_t)t*SLOT_SH + (2*wg)*512 + lane*8;
      short8 s0 = *reinterpret_cast<const short8*>(&tl[lane & 31][khalf]);
      short8 s1 = *reinterpret_cast<const short8*>(&tl[lane & 31][16 + khalf]);
      asm volatile("global_store_dwordx4 %0, %2, off sc0 sc1\n\t"
                   "global_store_dwordx4 %1, %3, off sc0 sc1"
                   :: "v"(ds), "v"(ds + 512), "v"(s0), "v"(s1) : "memory");
    }
    if (t+1 < TT){
      #pragma unroll
      for (int r=0;r<16;++r) u[r] = un[r];
    }
  }
}

// ---------------- epilogue: prior_in = d_shifted @ Wdz^T, fused KL -> atomicAdd ----------------
__global__ __launch_bounds__(256) void gemm_p_k(
    const float* __restrict__ dseq,           // dout: [32][1024][512] f32
    const unsigned short* __restrict__ Wdzp,  // [128][512] bf16
    const float* __restrict__ A,              // [32768][128] f32
    float* __restrict__ dout)
{
  __shared__ __align__(16) unsigned short Xs[128][40];
  __shared__ __align__(16) unsigned short Ws[128][40];
  __shared__ float Ls[128][128];
  __shared__ float red[256];
  const int bm = blockIdx.x;
  const int tid = threadIdx.x;
  const int lane = tid & 63;
  const int wv = tid >> 6;
  const int m0 = (wv >> 1) * 64, c0 = (wv & 1) * 64;
  f32x4 acc[4][4];
  #pragma unroll
  for (int i=0;i<4;++i)
    #pragma unroll
    for (int j=0;j<4;++j)
      #pragma unroll
      for (int r=0;r<4;++r) acc[i][j][r] = 0.f;

  const int sm = tid >> 1;
  const int sk = (tid & 1) * 16;
  for (int kt = 0; kt < 16; ++kt){
    __syncthreads();
    {
      int mg = bm*128 + sm;
      int ttm = mg & 1023;
      int srow = (ttm == 0) ? mg : (mg - 1);       // d[b][t-1]; t==0 rows overridden in KL
      const float* src = dseq + (size_t)srow*512u + (unsigned)(kt*32 + sk);
      uint2 o[4];
      #pragma unroll
      for (int q=0;q<4;++q){
        f32x4 v = *reinterpret_cast<const f32x4*>(src + 4*q);
        o[q].x = (unsigned)f2bf(v[0]) | ((unsigned)f2bf(v[1])<<16);
        o[q].y = (unsigned)f2bf(v[2]) | ((unsigned)f2bf(v[3])<<16);
      }
      *reinterpret_cast<uint4*>(&Xs[sm][sk])   = make_uint4(o[0].x,o[0].y,o[1].x,o[1].y);
      *reinterpret_cast<uint4*>(&Xs[sm][sk+8]) = make_uint4(o[2].x,o[2].y,o[3].x,o[3].y);
      const unsigned short* wsrc = Wdzp + (size_t)sm*512u + (unsigned)(kt*32 + sk);
      uint4 w0 = *reinterpret_cast<const uint4*>(wsrc);
      uint4 w1 = *reinterpret_cast<const uint4*>(wsrc + 8);
      *reinterpret_cast<uint4*>(&Ws[sm][sk])   = w0;
      *reinterpret_cast<uint4*>(&Ws[sm][sk+8]) = w1;
    }
    __syncthreads();
    short8 af[4], bf[4];
    #pragma unroll
    for (int i=0;i<4;++i)
      af[i] = *reinterpret_cast<const short8*>(&Xs[m0 + i*16 + (lane&15)][(lane>>4)*8]);
    #pragma unroll
    for (int j=0;j<4;++j)
      bf[j] = *reinterpret_cast<const short8*>(&Ws[c0 + j*16 + (lane&15)][(lane>>4)*8]);
    #pragma unroll
    for (int i=0;i<4;++i)
      #pragma unroll
      for (int j=0;j<4;++j)
        acc[i][j] = __builtin_amdgcn_mfma_f32_16x16x32_bf16(af[i], bf[j], acc[i][j], 0, 0, 0);
  }
  #pragma unroll
  for (int j=0;j<4;++j){
    int cc = c0 + j*16 + (lane&15);
    #pragma unroll
    for (int i=0;i<4;++i){
      int mm = m0 + i*16 + (lane>>4)*4;
      #pragma unroll
      for (int r=0;r<4;++r)
        Ls[mm + r][cc] = acc[i][j][r];
    }
  }
  __syncthreads();
  float ks = 0.f;
  const int z = tid & 63;
  for (int ml = (tid >> 6); ml < 128; ml += 4){
    int mg = bm*128 + ml;
    int ttm = mg & 1023;
    const float* ap = A + (size_t)mg*128u;
    float mq = fast_tanh(ap[z]);
    float sq = __expf(ap[64 + z]);
    float mp = (ttm == 0) ? 0.f : fast_tanh(Ls[ml][z]);
    float sp = (ttm == 0) ? 1.f : __expf(Ls[ml][64 + z]);
    float dm = mq - mp;
    ks += __logf(sp + 1e-6f) - __logf(sq + 1e-6f) - 0.5f
        + 0.5f*(dm*dm + sq*sq)/(sp*sp + 1e-6f);
  }
  red[tid] = ks; __syncthreads();
  for (int st = 128; st > 0; st >>= 1){
    if (tid < st) red[tid] += red[tid + st];
    __syncthreads();
  }
  if (tid == 0) atomicAdd(dout + (size_t)BTD, red[0] * (1e-3f/64.f));
}

extern "C" void kernel_launch(void* const* d_in, const int* in_sizes, int n_in,
                              void* d_out, int out_size, void* d_ws, size_t ws_size,
                              hipStream_t stream){
  const float* hd        = (const float*)d_in[0];
  const float* A         = (const float*)d_in[1];
  const float* noise     = (const float*)d_in[2];
  const float* Wd        = (const float*)d_in[3];
  const float* Wz        = (const float*)d_in[4];
  const float* Wdz       = (const float*)d_in[5];
  const float* Whd       = (const float*)d_in[6];
  const float* bias      = (const float*)d_in[7];
  const float* init_h    = (const float*)d_in[8];
  const float* init_h_mu = (const float*)d_in[9];
  float* dout = (float*)d_out;

  char* ws = (char*)d_ws;
  unsigned short* z_bf  = (unsigned short*)(ws);                      //  4,194,304 B
  unsigned short* Wu    = (unsigned short*)(ws + 4194304u);           //    589,824 B
  unsigned short* Wp    = (unsigned short*)(ws + 4784128u);           //    524,288 B
  unsigned short* Wdzp  = (unsigned short*)(ws + 5308416u);           //    131,072 B
  unsigned short* dinit = (unsigned short*)(ws + 5439488u);           //     32,768 B
  unsigned short* dcomm = (unsigned short*)(ws + 5472256u);           // 33,554,432 B (1024 slots)

  prep_ring_k<<<2048, 256, 0, stream>>>((uint4*)dcomm);
  prep_misc_k<<<1024, 256, 0, stream>>>(A, noise, Wd, Wz, Wdz, Whd, init_h,
                                        z_bf, Wu, Wp, Wdzp, dinit);
  wnll_k     <<<1,    256, 0, stream>>>(init_h, init_h_mu, dout);
  gemm_u_k   <<<1024, 256, 0, stream>>>(hd, z_bf, Wu, bias, dout);
  recur_k    <<<20,   256, 0, stream>>>(dout, init_h, Wp, dinit, dcomm);
  gemm_p_k   <<<256,  256, 0, stream>>>(dout, Wdzp, A, dout);
}